// Round 5
// baseline (234.968 us; speedup 1.0000x reference)
//
#include <hip/hip_runtime.h>
#include <hip/hip_bf16.h>
#include <stdint.h>

#define D_MODEL 768
#define N_HEADS 12
#define D_HEAD  64
#define BATCH   2
#define SEQ     2048
#define M_TOTAL (BATCH*SEQ)   /* 4096 */
#define N_QKV   (3*D_MODEL)   /* 2304 */

typedef float  floatx4 __attribute__((ext_vector_type(4)));
typedef short  shortx8 __attribute__((ext_vector_type(8)));

#if __has_builtin(__builtin_amdgcn_exp2f)
#define EXP2(x) __builtin_amdgcn_exp2f(x)
#else
#define EXP2(x) exp2f(x)
#endif

/* scale folded into Q: (1/sqrt(64)) * log2(e) so softmax runs in exp2 domain */
#define Q_SCALE 0.18033688011112042f

static __device__ __forceinline__ unsigned short f2bf(float f) {
  __hip_bfloat16 h = __float2bfloat16(f);
  return *reinterpret_cast<unsigned short*>(&h);
}

static __device__ __forceinline__ void gload_lds16(const void* g, void* l) {
  auto gp = reinterpret_cast<const uint32_t __attribute__((address_space(1)))*>(
      reinterpret_cast<uintptr_t>(g));
  auto lp = reinterpret_cast<uint32_t __attribute__((address_space(3)))*>(
      reinterpret_cast<uintptr_t>(l));
  __builtin_amdgcn_global_load_lds(gp, lp, 16, 0, 0);
}

/* ---------------- convert fp32 -> bf16 (x, W_qkv, W_o) ---------------- */
__global__ void convert_bf16_kernel(const float* __restrict__ x,
                                    const float* __restrict__ wqkv,
                                    const float* __restrict__ wo,
                                    unsigned short* __restrict__ xb,
                                    unsigned short* __restrict__ wqkvb,
                                    unsigned short* __restrict__ wob) {
  const int NX = M_TOTAL * D_MODEL / 4;   // 786432
  const int NW = N_QKV * D_MODEL / 4;     // 442368
  const int NO = D_MODEL * D_MODEL / 4;   // 147456
  const int total = NX + NW + NO;
  for (int i = blockIdx.x * blockDim.x + threadIdx.x; i < total;
       i += gridDim.x * blockDim.x) {
    const float4* src; unsigned short* dst; int j;
    if (i < NX)            { src = (const float4*)x;    dst = xb;    j = i; }
    else if (i < NX + NW)  { src = (const float4*)wqkv; dst = wqkvb; j = i - NX; }
    else                   { src = (const float4*)wo;   dst = wob;   j = i - NX - NW; }
    float4 v = src[j];
    ushort4 o;
    o.x = f2bf(v.x); o.y = f2bf(v.y); o.z = f2bf(v.z); o.w = f2bf(v.w);
    *(ushort4*)(dst + (size_t)j * 4) = o;
  }
}

/* ---------------- QKV projection GEMM: [4096,768] @ [2304,768]^T ----------------
   128x64 tile, 4 waves (wave-tile 64x32), 1152 blocks, XCD-chunked remap.
   Writes Q (scaled by Q_SCALE), K as [b,h,s,64] bf16; V transposed as [b,h,64,s]. */
__launch_bounds__(256, 4)
__global__ void qkv_gemm_kernel(const unsigned short* __restrict__ Xb,
                                const unsigned short* __restrict__ Wb,
                                const float* __restrict__ bias,
                                unsigned short* __restrict__ Qb,
                                unsigned short* __restrict__ Kb,
                                unsigned short* __restrict__ Vt) {
  __shared__ unsigned short Asub[128 * 32];
  __shared__ unsigned short Bsub[64 * 32];
  const int tid  = threadIdx.x;
  const int wave = tid >> 6;
  const int lane = tid & 63;
  /* 1152 blocks = 8 XCD chunks x 144 */
  const int flat = blockIdx.x;
  const int swz  = (flat & 7) * 144 + (flat >> 3);
  const int m0 = (swz / 36) * 128;
  const int n0 = (swz % 36) * 64;
  const int wm = (wave >> 1) * 64;
  const int wn = (wave & 1) * 32;
  const int srow = lane >> 2;          // 0..15
  const int scol = (lane & 3) * 8;     // k element offset
  const int col  = lane & 15;
  const int grp  = lane >> 4;
  floatx4 acc[4][2] = {};
  for (int kt = 0; kt < D_MODEL; kt += 32) {
    #pragma unroll
    for (int i = 0; i < 2; ++i) {
      int g = wave * 2 + i;
      gload_lds16(Xb + (size_t)(m0 + g * 16 + srow) * D_MODEL + kt + scol, &Asub[g * 512]);
    }
    gload_lds16(Wb + (size_t)(n0 + wave * 16 + srow) * D_MODEL + kt + scol, &Bsub[wave * 512]);
    __syncthreads();
    shortx8 af[4], bf[2];
    #pragma unroll
    for (int t = 0; t < 4; ++t)
      af[t] = *(const shortx8*)&Asub[(wm + t * 16 + col) * 32 + grp * 8];
    #pragma unroll
    for (int u = 0; u < 2; ++u)
      bf[u] = *(const shortx8*)&Bsub[(wn + u * 16 + col) * 32 + grp * 8];
    #pragma unroll
    for (int i = 0; i < 4; ++i)
      #pragma unroll
      for (int jj = 0; jj < 2; ++jj)
        acc[i][jj] = __builtin_amdgcn_mfma_f32_16x16x32_bf16(af[i], bf[jj], acc[i][jj], 0, 0, 0);
    __syncthreads();
  }
  /* epilogue: route to Q / K / Vt */
  #pragma unroll
  for (int i = 0; i < 4; ++i) {
    int mbase = m0 + wm + i * 16 + grp * 4;
    int b = mbase >> 11;
    int s = mbase & 2047;
    #pragma unroll
    for (int jj = 0; jj < 2; ++jj) {
      int n   = n0 + wn + jj * 16 + col;
      int sel = n / D_MODEL;
      int c   = n % D_MODEL;
      int h   = c >> 6, d = c & 63;
      int bh  = b * N_HEADS + h;
      float bv = bias[n];
      if (sel == 0) {
        #pragma unroll
        for (int r = 0; r < 4; ++r)
          Qb[((size_t)bh * SEQ + s + r) * D_HEAD + d] = f2bf((acc[i][jj][r] + bv) * Q_SCALE);
      } else if (sel == 1) {
        #pragma unroll
        for (int r = 0; r < 4; ++r)
          Kb[((size_t)bh * SEQ + s + r) * D_HEAD + d] = f2bf(acc[i][jj][r] + bv);
      } else {
        ushort4 o;
        o.x = f2bf(acc[i][jj][0] + bv);
        o.y = f2bf(acc[i][jj][1] + bv);
        o.z = f2bf(acc[i][jj][2] + bv);
        o.w = f2bf(acc[i][jj][3] + bv);
        *(ushort4*)&Vt[((size_t)bh * D_HEAD + d) * SEQ + s] = o;
      }
    }
  }
}

/* ---------------- causal flash attention ----------------
   1 wave per block, 16 q-rows per block, kv processed 128 per iteration
   (two independent 64-tiles -> 2x ILP in the latency chain, one softmax
   rescale round per 128 kv). 3072 blocks, XCD-chunked, longest-first.
   Swapped QK^T: lane holds S[kv][q=col]. P round-trips through padded-stride
   LDS (136 shorts/row -> bank-floor writes and reads). exp2 domain. */
__launch_bounds__(64, 3)
__global__ void attn_kernel(const unsigned short* __restrict__ Qb,
                            const unsigned short* __restrict__ Kb,
                            const unsigned short* __restrict__ Vt,
                            unsigned short* __restrict__ Zb) {
  __shared__ unsigned short pw[16 * 136];   // P tile, stride-padded
  const int lane = threadIdx.x;
  const int col = lane & 15;
  const int grp = lane >> 4;

  /* block -> (bh, j): XCD c = i&7 owns 3 heads; j descends (longest first). */
  const int i  = blockIdx.x;
  const int v  = (i & 7) * 384 + (i >> 3);
  const int bh = v >> 7;
  const int j  = 127 - (v & 127);
  const int q0 = j * 16;
  const int P  = (q0 + 16 + 127) >> 7;   // kv pair-tiles of 128

  const unsigned short* Qrow = Qb + ((size_t)bh * SEQ + q0 + col) * D_HEAD;
  shortx8 qf0 = *(const shortx8*)(Qrow + grp * 8);
  shortx8 qf1 = *(const shortx8*)(Qrow + 32 + grp * 8);

  floatx4 acc[4] = {};
  float mrun = -1e30f, lrun = 0.f;   // per-lane, q = q0 + col

  for (int p = 0; p < P; ++p) {
    const int kv0 = p * 128;
    /* S^T = K Q^T for both halves: lane holds S[kv=kv0+64h+16nt+4grp+r][q=q0+col] */
    floatx4 st[2][4];
    #pragma unroll
    for (int h = 0; h < 2; ++h)
      #pragma unroll
      for (int nt = 0; nt < 4; ++nt) {
        const unsigned short* Krow =
            Kb + ((size_t)bh * SEQ + kv0 + h * 64 + nt * 16 + col) * D_HEAD;
        shortx8 kf0 = *(const shortx8*)(Krow + grp * 8);
        shortx8 kf1 = *(const shortx8*)(Krow + 32 + grp * 8);
        floatx4 s = {};
        s = __builtin_amdgcn_mfma_f32_16x16x32_bf16(kf0, qf0, s, 0, 0, 0);
        s = __builtin_amdgcn_mfma_f32_16x16x32_bf16(kf1, qf1, s, 0, 0, 0);
        st[h][nt] = s;
      }
    /* causal mask: only the last pair can clip (128(P-1) <= q0 always) */
    float tmax = -1e30f;
    if (p == P - 1) {
      const int q = q0 + col;
      #pragma unroll
      for (int h = 0; h < 2; ++h)
        #pragma unroll
        for (int nt = 0; nt < 4; ++nt)
          #pragma unroll
          for (int r = 0; r < 4; ++r) {
            int kv = kv0 + h * 64 + nt * 16 + grp * 4 + r;
            float sv = (kv <= q) ? st[h][nt][r] : -1e30f;
            st[h][nt][r] = sv;
            tmax = fmaxf(tmax, sv);
          }
    } else {
      #pragma unroll
      for (int h = 0; h < 2; ++h)
        #pragma unroll
        for (int nt = 0; nt < 4; ++nt)
          #pragma unroll
          for (int r = 0; r < 4; ++r) tmax = fmaxf(tmax, st[h][nt][r]);
    }
    tmax = fmaxf(tmax, __shfl_xor(tmax, 16));
    tmax = fmaxf(tmax, __shfl_xor(tmax, 32));
    const float mnew  = fmaxf(mrun, tmax);
    const float alpha = EXP2(mrun - mnew);
    mrun = mnew;
    float rs = 0.f;
    #pragma unroll
    for (int h = 0; h < 2; ++h)
      #pragma unroll
      for (int nt = 0; nt < 4; ++nt)
        #pragma unroll
        for (int r = 0; r < 4; ++r) {
          float pv = EXP2(st[h][nt][r] - mnew);
          st[h][nt][r] = pv;
          rs += pv;
        }
    rs += __shfl_xor(rs, 16);
    rs += __shfl_xor(rs, 32);
    lrun = lrun * alpha + rs;
    /* rescale accumulator: alpha lives in col-space, acc rows are grp*4+r */
    #pragma unroll
    for (int r = 0; r < 4; ++r) {
      float ar = __shfl(alpha, grp * 4 + r);
      #pragma unroll
      for (int dn = 0; dn < 4; ++dn) acc[dn][r] *= ar;
    }
    /* P -> LDS: one b64 write per (h,nt); padded stride keeps banks at floor */
    #pragma unroll
    for (int h = 0; h < 2; ++h)
      #pragma unroll
      for (int nt = 0; nt < 4; ++nt) {
        ushort4 po;
        po.x = f2bf(st[h][nt][0]); po.y = f2bf(st[h][nt][1]);
        po.z = f2bf(st[h][nt][2]); po.w = f2bf(st[h][nt][3]);
        *(ushort4*)&pw[col * 136 + h * 64 + nt * 16 + grp * 4] = po;
      }
    /* Z += P V over the 128-kv pair: A-frag = P[q=col][kv=32m+8grp..+7] */
    #pragma unroll
    for (int m = 0; m < 4; ++m) {
      shortx8 pf = *(const shortx8*)&pw[col * 136 + m * 32 + grp * 8];
      #pragma unroll
      for (int dn = 0; dn < 4; ++dn) {
        const unsigned short* Vrow =
            Vt + ((size_t)bh * D_HEAD + dn * 16 + col) * SEQ + kv0 + m * 32 + grp * 8;
        shortx8 vf = *(const shortx8*)Vrow;
        acc[dn] = __builtin_amdgcn_mfma_f32_16x16x32_bf16(pf, vf, acc[dn], 0, 0, 0);
      }
    }
  }
  /* normalize (lrun is col-space; acc rows are grp*4+r) and write Z */
  const int b = bh / N_HEADS, h = bh % N_HEADS;
  #pragma unroll
  for (int r = 0; r < 4; ++r) {
    float lr = __shfl(lrun, grp * 4 + r);
    float li = 1.0f / lr;
    int q = q0 + grp * 4 + r;
    #pragma unroll
    for (int dn = 0; dn < 4; ++dn)
      Zb[((size_t)b * SEQ + q) * D_MODEL + h * 64 + dn * 16 + col] = f2bf(acc[dn][r] * li);
  }
}

/* ---------------- output projection: [4096,768] @ [768,768]^T + b_o -> fp32 ----
   64x64 tile, 4 waves (wave-tile 32x32), 768 blocks (3/CU), XCD-chunked. */
__launch_bounds__(256, 4)
__global__ void out_gemm_kernel(const unsigned short* __restrict__ Zb,
                                const unsigned short* __restrict__ Wob,
                                const float* __restrict__ bo,
                                float* __restrict__ Out) {
  __shared__ unsigned short Asub[64 * 32];
  __shared__ unsigned short Bsub[64 * 32];
  const int tid  = threadIdx.x;
  const int wave = tid >> 6;
  const int lane = tid & 63;
  /* 768 blocks = 8 XCD chunks x 96 */
  const int flat = blockIdx.x;
  const int swz  = (flat & 7) * 96 + (flat >> 3);
  const int m0 = (swz / 12) * 64;
  const int n0 = (swz % 12) * 64;
  const int wm = (wave >> 1) * 32;
  const int wn = (wave & 1) * 32;
  const int srow = lane >> 2;
  const int scol = (lane & 3) * 8;
  const int col  = lane & 15;
  const int grp  = lane >> 4;
  floatx4 acc[2][2] = {};
  for (int kt = 0; kt < D_MODEL; kt += 32) {
    gload_lds16(Zb  + (size_t)(m0 + wave * 16 + srow) * D_MODEL + kt + scol, &Asub[wave * 512]);
    gload_lds16(Wob + (size_t)(n0 + wave * 16 + srow) * D_MODEL + kt + scol, &Bsub[wave * 512]);
    __syncthreads();
    shortx8 af[2], bf[2];
    #pragma unroll
    for (int t = 0; t < 2; ++t) {
      af[t] = *(const shortx8*)&Asub[(wm + t * 16 + col) * 32 + grp * 8];
      bf[t] = *(const shortx8*)&Bsub[(wn + t * 16 + col) * 32 + grp * 8];
    }
    #pragma unroll
    for (int i = 0; i < 2; ++i)
      #pragma unroll
      for (int jj = 0; jj < 2; ++jj)
        acc[i][jj] = __builtin_amdgcn_mfma_f32_16x16x32_bf16(af[i], bf[jj], acc[i][jj], 0, 0, 0);
    __syncthreads();
  }
  #pragma unroll
  for (int i = 0; i < 2; ++i) {
    int mbase = m0 + wm + i * 16 + grp * 4;
    #pragma unroll
    for (int jj = 0; jj < 2; ++jj) {
      int n = n0 + wn + jj * 16 + col;
      float bv = bo[n];
      #pragma unroll
      for (int r = 0; r < 4; ++r)
        Out[(size_t)(mbase + r) * D_MODEL + n] = acc[i][jj][r] + bv;
    }
  }
}

/* ---------------- launcher ---------------- */
extern "C" void kernel_launch(void* const* d_in, const int* in_sizes, int n_in,
                              void* d_out, int out_size, void* d_ws, size_t ws_size,
                              hipStream_t stream) {
  const float* x    = (const float*)d_in[0];
  const float* Wqkv = (const float*)d_in[1];
  const float* bqkv = (const float*)d_in[2];
  const float* Wo   = (const float*)d_in[3];
  const float* bo   = (const float*)d_in[4];
  float* out = (float*)d_out;

  unsigned short* ws = (unsigned short*)d_ws;
  const size_t SZ_X   = (size_t)M_TOTAL * D_MODEL;   // 3,145,728
  const size_t SZ_WQ  = (size_t)N_QKV * D_MODEL;     // 1,769,472
  const size_t SZ_WO  = (size_t)D_MODEL * D_MODEL;   //   589,824
  unsigned short* Xb    = ws;
  unsigned short* Wqkvb = Xb + SZ_X;
  unsigned short* Wob   = Wqkvb + SZ_WQ;
  unsigned short* Qb    = Wob + SZ_WO;
  unsigned short* Kb    = Qb + SZ_X;
  unsigned short* Vt    = Kb + SZ_X;
  unsigned short* Zb    = Vt + SZ_X;

  convert_bf16_kernel<<<dim3(1024), dim3(256), 0, stream>>>(x, Wqkv, Wo, Xb, Wqkvb, Wob);
  qkv_gemm_kernel<<<dim3((N_QKV / 64) * (M_TOTAL / 128)), dim3(256), 0, stream>>>(
      Xb, Wqkvb, bqkv, Qb, Kb, Vt);
  attn_kernel<<<dim3(128 * BATCH * N_HEADS), dim3(64), 0, stream>>>(Qb, Kb, Vt, Zb);
  out_gemm_kernel<<<dim3((D_MODEL / 64) * (M_TOTAL / 64)), dim3(256), 0, stream>>>(
      Zb, Wob, bo, out);
}

// Round 11
// 179.830 us; speedup vs baseline: 1.3066x; 1.3066x over previous
//
#include <hip/hip_runtime.h>
#include <hip/hip_bf16.h>
#include <stdint.h>

#define D_MODEL 768
#define N_HEADS 12
#define D_HEAD  64
#define BATCH   2
#define SEQ     2048
#define M_TOTAL (BATCH*SEQ)   /* 4096 */
#define N_QKV   (3*D_MODEL)   /* 2304 */

typedef float  floatx4 __attribute__((ext_vector_type(4)));
typedef short  shortx8 __attribute__((ext_vector_type(8)));

#if __has_builtin(__builtin_amdgcn_exp2f)
#define EXP2(x) __builtin_amdgcn_exp2f(x)
#else
#define EXP2(x) exp2f(x)
#endif

/* scale folded into Q: (1/sqrt(64)) * log2(e) so softmax runs in exp2 domain */
#define Q_SCALE 0.18033688011112042f

static __device__ __forceinline__ unsigned short f2bf(float f) {
  __hip_bfloat16 h = __float2bfloat16(f);
  return *reinterpret_cast<unsigned short*>(&h);
}

static __device__ __forceinline__ void gload_lds16(const void* g, void* l) {
  auto gp = reinterpret_cast<const uint32_t __attribute__((address_space(1)))*>(
      reinterpret_cast<uintptr_t>(g));
  auto lp = reinterpret_cast<uint32_t __attribute__((address_space(3)))*>(
      reinterpret_cast<uintptr_t>(l));
  __builtin_amdgcn_global_load_lds(gp, lp, 16, 0, 0);
}

/* ---------------- convert fp32 -> bf16 (x, W_qkv, W_o) ---------------- */
__global__ void convert_bf16_kernel(const float* __restrict__ x,
                                    const float* __restrict__ wqkv,
                                    const float* __restrict__ wo,
                                    unsigned short* __restrict__ xb,
                                    unsigned short* __restrict__ wqkvb,
                                    unsigned short* __restrict__ wob) {
  const int NX = M_TOTAL * D_MODEL / 4;   // 786432
  const int NW = N_QKV * D_MODEL / 4;     // 442368
  const int NO = D_MODEL * D_MODEL / 4;   // 147456
  const int total = NX + NW + NO;
  for (int i = blockIdx.x * blockDim.x + threadIdx.x; i < total;
       i += gridDim.x * blockDim.x) {
    const float4* src; unsigned short* dst; int j;
    if (i < NX)            { src = (const float4*)x;    dst = xb;    j = i; }
    else if (i < NX + NW)  { src = (const float4*)wqkv; dst = wqkvb; j = i - NX; }
    else                   { src = (const float4*)wo;   dst = wob;   j = i - NX - NW; }
    float4 v = src[j];
    ushort4 o;
    o.x = f2bf(v.x); o.y = f2bf(v.y); o.z = f2bf(v.z); o.w = f2bf(v.w);
    *(ushort4*)(dst + (size_t)j * 4) = o;
  }
}

/* ---------------- QKV projection GEMM: [4096,768] @ [2304,768]^T ----------------
   128x64 tile, 4 waves (wave-tile 64x32), 1152 blocks, XCD-chunked remap.
   Writes Q (scaled by Q_SCALE), K as [b,h,s,64] bf16; V transposed as [b,h,64,s]. */
__launch_bounds__(256, 4)
__global__ void qkv_gemm_kernel(const unsigned short* __restrict__ Xb,
                                const unsigned short* __restrict__ Wb,
                                const float* __restrict__ bias,
                                unsigned short* __restrict__ Qb,
                                unsigned short* __restrict__ Kb,
                                unsigned short* __restrict__ Vt) {
  __shared__ unsigned short Asub[128 * 32];
  __shared__ unsigned short Bsub[64 * 32];
  const int tid  = threadIdx.x;
  const int wave = tid >> 6;
  const int lane = tid & 63;
  /* 1152 blocks = 8 XCD chunks x 144 */
  const int flat = blockIdx.x;
  const int swz  = (flat & 7) * 144 + (flat >> 3);
  const int m0 = (swz / 36) * 128;
  const int n0 = (swz % 36) * 64;
  const int wm = (wave >> 1) * 64;
  const int wn = (wave & 1) * 32;
  const int srow = lane >> 2;          // 0..15
  const int scol = (lane & 3) * 8;     // k element offset
  const int col  = lane & 15;
  const int grp  = lane >> 4;
  floatx4 acc[4][2] = {};
  for (int kt = 0; kt < D_MODEL; kt += 32) {
    #pragma unroll
    for (int i = 0; i < 2; ++i) {
      int g = wave * 2 + i;
      gload_lds16(Xb + (size_t)(m0 + g * 16 + srow) * D_MODEL + kt + scol, &Asub[g * 512]);
    }
    gload_lds16(Wb + (size_t)(n0 + wave * 16 + srow) * D_MODEL + kt + scol, &Bsub[wave * 512]);
    __syncthreads();
    shortx8 af[4], bf[2];
    #pragma unroll
    for (int t = 0; t < 4; ++t)
      af[t] = *(const shortx8*)&Asub[(wm + t * 16 + col) * 32 + grp * 8];
    #pragma unroll
    for (int u = 0; u < 2; ++u)
      bf[u] = *(const shortx8*)&Bsub[(wn + u * 16 + col) * 32 + grp * 8];
    #pragma unroll
    for (int i = 0; i < 4; ++i)
      #pragma unroll
      for (int jj = 0; jj < 2; ++jj)
        acc[i][jj] = __builtin_amdgcn_mfma_f32_16x16x32_bf16(af[i], bf[jj], acc[i][jj], 0, 0, 0);
    __syncthreads();
  }
  /* epilogue: route to Q / K / Vt */
  #pragma unroll
  for (int i = 0; i < 4; ++i) {
    int mbase = m0 + wm + i * 16 + grp * 4;
    int b = mbase >> 11;
    int s = mbase & 2047;
    #pragma unroll
    for (int jj = 0; jj < 2; ++jj) {
      int n   = n0 + wn + jj * 16 + col;
      int sel = n / D_MODEL;
      int c   = n % D_MODEL;
      int h   = c >> 6, d = c & 63;
      int bh  = b * N_HEADS + h;
      float bv = bias[n];
      if (sel == 0) {
        #pragma unroll
        for (int r = 0; r < 4; ++r)
          Qb[((size_t)bh * SEQ + s + r) * D_HEAD + d] = f2bf((acc[i][jj][r] + bv) * Q_SCALE);
      } else if (sel == 1) {
        #pragma unroll
        for (int r = 0; r < 4; ++r)
          Kb[((size_t)bh * SEQ + s + r) * D_HEAD + d] = f2bf(acc[i][jj][r] + bv);
      } else {
        ushort4 o;
        o.x = f2bf(acc[i][jj][0] + bv);
        o.y = f2bf(acc[i][jj][1] + bv);
        o.z = f2bf(acc[i][jj][2] + bv);
        o.w = f2bf(acc[i][jj][3] + bv);
        *(ushort4*)&Vt[((size_t)bh * D_HEAD + d) * SEQ + s] = o;
      }
    }
  }
}

/* ---------------- causal flash attention ----------------
   4 waves/block, QBLK=64 (16 q-rows per wave), KVBLK=64 staged in LDS,
   double-buffered via global_load_lds (T3-min schedule, 1 barrier/tile).
   K/V LDS tiles are [row][128B] with XOR swizzle byte^=((row&7)<<4) realized
   by pre-swizzling the per-lane GLOBAL source (linear LDS dest) and applying
   the same XOR on the ds_read side (involution). Swapped QK^T: lane holds
   S[kv][q=col]; P transposes through per-wave padded LDS. exp2 domain.
   768 blocks = 8 XCD chunks x 3 heads, longest-first; 49 KB LDS -> 3 blk/CU. */
__launch_bounds__(256, 3)
__global__ void attn_kernel(const unsigned short* __restrict__ Qb,
                            const unsigned short* __restrict__ Kb,
                            const unsigned short* __restrict__ Vt,
                            unsigned short* __restrict__ Zb) {
  __shared__ unsigned short K_lds[2][64 * 64];
  __shared__ unsigned short V_lds[2][64 * 64];
  __shared__ unsigned short pw[4][16 * 136];
  const int tid  = threadIdx.x;
  const int w    = tid >> 6;
  const int lane = tid & 63;
  const int col  = lane & 15;
  const int grp  = lane >> 4;

  /* block map: 768 = 8 XCD chunks x 96 (3 heads each); qb descends (longest first) */
  const int i  = blockIdx.x;
  const int v  = (i & 7) * 96 + (i >> 3);
  const int bh = v >> 5;
  const int qb = 31 - (v & 31);
  const int q0 = qb * 64;
  const int qgb = q0 + w * 16;          // this wave's first q row
  const int ntiles = qb + 1;

  /* Q fragments for rows qgb+col (pre-scaled by Q_SCALE at QKV epilogue) */
  const unsigned short* Qrow = Qb + ((size_t)bh * SEQ + qgb + col) * D_HEAD;
  const shortx8 qf0 = *(const shortx8*)(Qrow + grp * 8);
  const shortx8 qf1 = *(const shortx8*)(Qrow + 32 + grp * 8);

  const size_t kbase = (size_t)bh * SEQ * D_HEAD;      // K element base for head
  const size_t vbase = (size_t)bh * D_HEAD * SEQ;      // Vt element base for head

  floatx4 acc[4] = {};
  float mrun = -1e30f, lrun = 0.f;      // per-lane state for q = qgb + col
  unsigned short* pwv = pw[w];

  /* stage tile kv0 into buffer buf: each wave moves 2KB of K + 2KB of V.
     Linear LDS dest; global source pre-swizzled so LDS holds byte^((row&7)<<4). */
#define STAGE(buf, kv0) do {                                                   \
    const size_t kg = kbase + (size_t)(kv0) * D_HEAD;                          \
    _Pragma("unroll")                                                          \
    for (int s_ = 0; s_ < 2; ++s_) {                                           \
      int L_ = w * 2048 + s_ * 1024 + lane * 16;                               \
      int g_ = L_ ^ (((L_ >> 7) & 7) << 4);                                    \
      gload_lds16(Kb + kg + (g_ >> 1), &K_lds[buf][w * 1024 + s_ * 512]);      \
      int row_ = g_ >> 7, cb_ = g_ & 127;                                      \
      gload_lds16(Vt + vbase + (size_t)row_ * SEQ + (kv0) + (cb_ >> 1),        \
                  &V_lds[buf][w * 1024 + s_ * 512]);                           \
    }                                                                          \
  } while (0)

  STAGE(0, 0);
  __syncthreads();

  for (int t = 0; t < ntiles; ++t) {
    const int cur = t & 1;
    const int kv0 = t * 64;
    if (t + 1 < ntiles) STAGE(cur ^ 1, (t + 1) * 64);

    /* S^T = K Q^T : lane holds S[kv = kv0+16nt+4grp+r][q = qgb+col] */
    floatx4 st[4];
    #pragma unroll
    for (int nt = 0; nt < 4; ++nt) {
      int r0 = (nt * 16 + col) * 64;
      int sw = (col & 7) << 3;
      shortx8 kf0 = *(const shortx8*)&K_lds[cur][(r0 + grp * 8) ^ sw];
      shortx8 kf1 = *(const shortx8*)&K_lds[cur][(r0 + 32 + grp * 8) ^ sw];
      floatx4 s = {};
      s = __builtin_amdgcn_mfma_f32_16x16x32_bf16(kf0, qf0, s, 0, 0, 0);
      s = __builtin_amdgcn_mfma_f32_16x16x32_bf16(kf1, qf1, s, 0, 0, 0);
      st[nt] = s;
    }
    /* causal mask: only the last tile (kv0 == q0) can clip this wave's rows */
    float tmax = -1e30f;
    if (t == ntiles - 1) {
      const int q = qgb + col;
      #pragma unroll
      for (int nt = 0; nt < 4; ++nt)
        #pragma unroll
        for (int r = 0; r < 4; ++r) {
          int kv = kv0 + nt * 16 + grp * 4 + r;
          float sv = (kv <= q) ? st[nt][r] : -1e30f;
          st[nt][r] = sv;
          tmax = fmaxf(tmax, sv);
        }
    } else {
      #pragma unroll
      for (int nt = 0; nt < 4; ++nt)
        #pragma unroll
        for (int r = 0; r < 4; ++r) tmax = fmaxf(tmax, st[nt][r]);
    }
    tmax = fmaxf(tmax, __shfl_xor(tmax, 16));
    tmax = fmaxf(tmax, __shfl_xor(tmax, 32));
    const float mnew  = fmaxf(mrun, tmax);
    const float alpha = EXP2(mrun - mnew);
    mrun = mnew;
    float rs = 0.f;
    #pragma unroll
    for (int nt = 0; nt < 4; ++nt)
      #pragma unroll
      for (int r = 0; r < 4; ++r) {
        float pv = EXP2(st[nt][r] - mnew);
        st[nt][r] = pv;
        rs += pv;
      }
    rs += __shfl_xor(rs, 16);
    rs += __shfl_xor(rs, 32);
    lrun = lrun * alpha + rs;
    /* rescale accumulator: alpha lives in col-space, acc rows are grp*4+r */
    #pragma unroll
    for (int r = 0; r < 4; ++r) {
      float ar = __shfl(alpha, grp * 4 + r);
      #pragma unroll
      for (int dn = 0; dn < 4; ++dn) acc[dn][r] *= ar;
    }
    /* P -> per-wave LDS (transpose): lane's 4 r-values are consecutive kv */
    #pragma unroll
    for (int nt = 0; nt < 4; ++nt) {
      ushort4 po;
      po.x = f2bf(st[nt][0]); po.y = f2bf(st[nt][1]);
      po.z = f2bf(st[nt][2]); po.w = f2bf(st[nt][3]);
      *(ushort4*)&pwv[col * 136 + nt * 16 + grp * 4] = po;
    }
    /* Z += P V from LDS: A = P[q=col][kv=32m+8grp..], B = V[d=16dn+col][kv] */
    #pragma unroll
    for (int m = 0; m < 2; ++m) {
      shortx8 pf = *(const shortx8*)&pwv[col * 136 + m * 32 + grp * 8];
      #pragma unroll
      for (int dn = 0; dn < 4; ++dn) {
        int vr = (dn * 16 + col) * 64;
        shortx8 vf = *(const shortx8*)&V_lds[cur][(vr + m * 32 + grp * 8) ^ ((col & 7) << 3)];
        acc[dn] = __builtin_amdgcn_mfma_f32_16x16x32_bf16(pf, vf, acc[dn], 0, 0, 0);
      }
    }
    __syncthreads();   /* next tile staged (vmcnt drain) + everyone done with cur */
  }
#undef STAGE

  /* normalize (lrun is col-space; acc rows are grp*4+r) and write Z */
  const int b = bh / N_HEADS, h = bh % N_HEADS;
  #pragma unroll
  for (int r = 0; r < 4; ++r) {
    float lr = __shfl(lrun, grp * 4 + r);
    float li = 1.0f / lr;
    int q = qgb + grp * 4 + r;
    #pragma unroll
    for (int dn = 0; dn < 4; ++dn)
      Zb[((size_t)b * SEQ + q) * D_MODEL + h * 64 + dn * 16 + col] = f2bf(acc[dn][r] * li);
  }
}

/* ---------------- output projection: [4096,768] @ [768,768]^T + b_o -> fp32 ----
   64x64 tile, 4 waves (wave-tile 32x32), 768 blocks (3/CU), XCD-chunked. */
__launch_bounds__(256, 4)
__global__ void out_gemm_kernel(const unsigned short* __restrict__ Zb,
                                const unsigned short* __restrict__ Wob,
                                const float* __restrict__ bo,
                                float* __restrict__ Out) {
  __shared__ unsigned short Asub[64 * 32];
  __shared__ unsigned short Bsub[64 * 32];
  const int tid  = threadIdx.x;
  const int wave = tid >> 6;
  const int lane = tid & 63;
  /* 768 blocks = 8 XCD chunks x 96 */
  const int flat = blockIdx.x;
  const int swz  = (flat & 7) * 96 + (flat >> 3);
  const int m0 = (swz / 12) * 64;
  const int n0 = (swz % 12) * 64;
  const int wm = (wave >> 1) * 32;
  const int wn = (wave & 1) * 32;
  const int srow = lane >> 2;
  const int scol = (lane & 3) * 8;
  const int col  = lane & 15;
  const int grp  = lane >> 4;
  floatx4 acc[2][2] = {};
  for (int kt = 0; kt < D_MODEL; kt += 32) {
    gload_lds16(Zb  + (size_t)(m0 + wave * 16 + srow) * D_MODEL + kt + scol, &Asub[wave * 512]);
    gload_lds16(Wob + (size_t)(n0 + wave * 16 + srow) * D_MODEL + kt + scol, &Bsub[wave * 512]);
    __syncthreads();
    shortx8 af[2], bf[2];
    #pragma unroll
    for (int t = 0; t < 2; ++t) {
      af[t] = *(const shortx8*)&Asub[(wm + t * 16 + col) * 32 + grp * 8];
      bf[t] = *(const shortx8*)&Bsub[(wn + t * 16 + col) * 32 + grp * 8];
    }
    #pragma unroll
    for (int i = 0; i < 2; ++i)
      #pragma unroll
      for (int jj = 0; jj < 2; ++jj)
        acc[i][jj] = __builtin_amdgcn_mfma_f32_16x16x32_bf16(af[i], bf[jj], acc[i][jj], 0, 0, 0);
    __syncthreads();
  }
  #pragma unroll
  for (int i = 0; i < 2; ++i) {
    int mbase = m0 + wm + i * 16 + grp * 4;
    #pragma unroll
    for (int jj = 0; jj < 2; ++jj) {
      int n = n0 + wn + jj * 16 + col;
      float bv = bo[n];
      #pragma unroll
      for (int r = 0; r < 4; ++r)
        Out[(size_t)(mbase + r) * D_MODEL + n] = acc[i][jj][r] + bv;
    }
  }
}

/* ---------------- launcher ---------------- */
extern "C" void kernel_launch(void* const* d_in, const int* in_sizes, int n_in,
                              void* d_out, int out_size, void* d_ws, size_t ws_size,
                              hipStream_t stream) {
  const float* x    = (const float*)d_in[0];
  const float* Wqkv = (const float*)d_in[1];
  const float* bqkv = (const float*)d_in[2];
  const float* Wo   = (const float*)d_in[3];
  const float* bo   = (const float*)d_in[4];
  float* out = (float*)d_out;

  unsigned short* ws = (unsigned short*)d_ws;
  const size_t SZ_X   = (size_t)M_TOTAL * D_MODEL;   // 3,145,728
  const size_t SZ_WQ  = (size_t)N_QKV * D_MODEL;     // 1,769,472
  const size_t SZ_WO  = (size_t)D_MODEL * D_MODEL;   //   589,824
  unsigned short* Xb    = ws;
  unsigned short* Wqkvb = Xb + SZ_X;
  unsigned short* Wob   = Wqkvb + SZ_WQ;
  unsigned short* Qb    = Wob + SZ_WO;
  unsigned short* Kb    = Qb + SZ_X;
  unsigned short* Vt    = Kb + SZ_X;
  unsigned short* Zb    = Vt + SZ_X;

  convert_bf16_kernel<<<dim3(1024), dim3(256), 0, stream>>>(x, Wqkv, Wo, Xb, Wqkvb, Wob);
  qkv_gemm_kernel<<<dim3((N_QKV / 64) * (M_TOTAL / 128)), dim3(256), 0, stream>>>(
      Xb, Wqkvb, bqkv, Qb, Kb, Vt);
  attn_kernel<<<dim3(8 * 96), dim3(256), 0, stream>>>(Qb, Kb, Vt, Zb);
  out_gemm_kernel<<<dim3((D_MODEL / 64) * (M_TOTAL / 64)), dim3(256), 0, stream>>>(
      Zb, Wob, bo, out);
}

// Round 12
// 170.517 us; speedup vs baseline: 1.3780x; 1.0546x over previous
//
#include <hip/hip_runtime.h>
#include <hip/hip_bf16.h>
#include <stdint.h>

#define D_MODEL 768
#define N_HEADS 12
#define D_HEAD  64
#define BATCH   2
#define SEQ     2048
#define M_TOTAL (BATCH*SEQ)   /* 4096 */
#define N_QKV   (3*D_MODEL)   /* 2304 */

typedef float  floatx4 __attribute__((ext_vector_type(4)));
typedef short  shortx8 __attribute__((ext_vector_type(8)));

#if __has_builtin(__builtin_amdgcn_exp2f)
#define EXP2(x) __builtin_amdgcn_exp2f(x)
#else
#define EXP2(x) exp2f(x)
#endif

/* scale folded into Q: (1/sqrt(64)) * log2(e) so softmax runs in exp2 domain */
#define Q_SCALE 0.18033688011112042f

static __device__ __forceinline__ unsigned short f2bf(float f) {
  __hip_bfloat16 h = __float2bfloat16(f);
  return *reinterpret_cast<unsigned short*>(&h);
}

static __device__ __forceinline__ void gload_lds16(const void* g, void* l) {
  auto gp = reinterpret_cast<const uint32_t __attribute__((address_space(1)))*>(
      reinterpret_cast<uintptr_t>(g));
  auto lp = reinterpret_cast<uint32_t __attribute__((address_space(3)))*>(
      reinterpret_cast<uintptr_t>(l));
  __builtin_amdgcn_global_load_lds(gp, lp, 16, 0, 0);
}

/* ---------------- convert fp32 -> bf16 (x, W_qkv, W_o) ---------------- */
__global__ void convert_bf16_kernel(const float* __restrict__ x,
                                    const float* __restrict__ wqkv,
                                    const float* __restrict__ wo,
                                    unsigned short* __restrict__ xb,
                                    unsigned short* __restrict__ wqkvb,
                                    unsigned short* __restrict__ wob) {
  const int NX = M_TOTAL * D_MODEL / 4;   // 786432
  const int NW = N_QKV * D_MODEL / 4;     // 442368
  const int NO = D_MODEL * D_MODEL / 4;   // 147456
  const int total = NX + NW + NO;
  for (int i = blockIdx.x * blockDim.x + threadIdx.x; i < total;
       i += gridDim.x * blockDim.x) {
    const float4* src; unsigned short* dst; int j;
    if (i < NX)            { src = (const float4*)x;    dst = xb;    j = i; }
    else if (i < NX + NW)  { src = (const float4*)wqkv; dst = wqkvb; j = i - NX; }
    else                   { src = (const float4*)wo;   dst = wob;   j = i - NX - NW; }
    float4 v = src[j];
    ushort4 o;
    o.x = f2bf(v.x); o.y = f2bf(v.y); o.z = f2bf(v.z); o.w = f2bf(v.w);
    *(ushort4*)(dst + (size_t)j * 4) = o;
  }
}

/* ---------------- QKV projection GEMM: [4096,768] @ [2304,768]^T ----------------
   m97-style 128x128 tile, BK=32, 4 waves (2x2, each 64x64, 4x4 acc).
   576 blocks = 8 XCD chunks x 72. Writes Q (scaled), K [b,h,s,64], Vt [b,h,64,s]. */
__launch_bounds__(256, 3)
__global__ void qkv_gemm_kernel(const unsigned short* __restrict__ Xb,
                                const unsigned short* __restrict__ Wb,
                                const float* __restrict__ bias,
                                unsigned short* __restrict__ Qb,
                                unsigned short* __restrict__ Kb,
                                unsigned short* __restrict__ Vt) {
  __shared__ unsigned short Asub[128 * 32];
  __shared__ unsigned short Bsub[128 * 32];
  const int tid  = threadIdx.x;
  const int wave = tid >> 6;
  const int lane = tid & 63;
  /* 576 blocks = 8 XCD chunks x 72 */
  const int flat = blockIdx.x;
  const int swz  = (flat & 7) * 72 + (flat >> 3);
  const int m0 = (swz / 18) * 128;
  const int n0 = (swz % 18) * 128;
  const int wm = (wave >> 1) * 64;
  const int wn = (wave & 1) * 64;
  const int srow = lane >> 2;          // 0..15
  const int scol = (lane & 3) * 8;     // k element offset
  const int col  = lane & 15;
  const int grp  = lane >> 4;
  floatx4 acc[4][4] = {};
  for (int kt = 0; kt < D_MODEL; kt += 32) {
    #pragma unroll
    for (int i = 0; i < 2; ++i) {
      int c = wave * 2 + i;
      int row = c * 16 + srow;
      gload_lds16(Xb + (size_t)(m0 + row) * D_MODEL + kt + scol, &Asub[c * 512]);
      gload_lds16(Wb + (size_t)(n0 + row) * D_MODEL + kt + scol, &Bsub[c * 512]);
    }
    __syncthreads();
    shortx8 af[4], bf[4];
    #pragma unroll
    for (int t = 0; t < 4; ++t) {
      af[t] = *(const shortx8*)&Asub[(wm + t * 16 + col) * 32 + grp * 8];
      bf[t] = *(const shortx8*)&Bsub[(wn + t * 16 + col) * 32 + grp * 8];
    }
    #pragma unroll
    for (int i = 0; i < 4; ++i)
      #pragma unroll
      for (int j = 0; j < 4; ++j)
        acc[i][j] = __builtin_amdgcn_mfma_f32_16x16x32_bf16(af[i], bf[j], acc[i][j], 0, 0, 0);
    __syncthreads();
  }
  /* epilogue: route to Q / K / Vt */
  #pragma unroll
  for (int i = 0; i < 4; ++i) {
    int mbase = m0 + wm + i * 16 + grp * 4;
    int b = mbase >> 11;
    int s = mbase & 2047;
    #pragma unroll
    for (int j = 0; j < 4; ++j) {
      int n   = n0 + wn + j * 16 + col;
      int sel = n / D_MODEL;
      int c   = n % D_MODEL;
      int h   = c >> 6, d = c & 63;
      int bh  = b * N_HEADS + h;
      float bv = bias[n];
      if (sel == 0) {
        #pragma unroll
        for (int r = 0; r < 4; ++r)
          Qb[((size_t)bh * SEQ + s + r) * D_HEAD + d] = f2bf((acc[i][j][r] + bv) * Q_SCALE);
      } else if (sel == 1) {
        #pragma unroll
        for (int r = 0; r < 4; ++r)
          Kb[((size_t)bh * SEQ + s + r) * D_HEAD + d] = f2bf(acc[i][j][r] + bv);
      } else {
        ushort4 o;
        o.x = f2bf(acc[i][j][0] + bv);
        o.y = f2bf(acc[i][j][1] + bv);
        o.z = f2bf(acc[i][j][2] + bv);
        o.w = f2bf(acc[i][j][3] + bv);
        *(ushort4*)&Vt[((size_t)bh * D_HEAD + d) * SEQ + s] = o;
      }
    }
  }
}

/* ---------------- causal flash attention ----------------
   4 waves/block, QBLK=64 (16 q-rows per wave), KVBLK=64 staged in LDS,
   double-buffered via global_load_lds (T3-min schedule, 1 barrier/tile).
   K/V LDS tiles are [row][128B] with XOR swizzle byte^=((row&7)<<4) realized
   by pre-swizzling the per-lane GLOBAL source (linear LDS dest) and applying
   the same XOR on the ds_read side (involution). Swapped QK^T: lane holds
   S[kv][q=col]; P transposes through per-wave padded LDS. exp2 domain.
   768 blocks = 8 XCD chunks x 3 heads, longest-first; 49 KB LDS -> 3 blk/CU. */
__launch_bounds__(256, 3)
__global__ void attn_kernel(const unsigned short* __restrict__ Qb,
                            const unsigned short* __restrict__ Kb,
                            const unsigned short* __restrict__ Vt,
                            unsigned short* __restrict__ Zb) {
  __shared__ unsigned short K_lds[2][64 * 64];
  __shared__ unsigned short V_lds[2][64 * 64];
  __shared__ unsigned short pw[4][16 * 136];
  const int tid  = threadIdx.x;
  const int w    = tid >> 6;
  const int lane = tid & 63;
  const int col  = lane & 15;
  const int grp  = lane >> 4;

  /* block map: 768 = 8 XCD chunks x 96 (3 heads each); qb descends (longest first) */
  const int i  = blockIdx.x;
  const int v  = (i & 7) * 96 + (i >> 3);
  const int bh = v >> 5;
  const int qb = 31 - (v & 31);
  const int q0 = qb * 64;
  const int qgb = q0 + w * 16;          // this wave's first q row
  const int ntiles = qb + 1;

  /* Q fragments for rows qgb+col (pre-scaled by Q_SCALE at QKV epilogue) */
  const unsigned short* Qrow = Qb + ((size_t)bh * SEQ + qgb + col) * D_HEAD;
  const shortx8 qf0 = *(const shortx8*)(Qrow + grp * 8);
  const shortx8 qf1 = *(const shortx8*)(Qrow + 32 + grp * 8);

  const size_t kbase = (size_t)bh * SEQ * D_HEAD;      // K element base for head
  const size_t vbase = (size_t)bh * D_HEAD * SEQ;      // Vt element base for head

  floatx4 acc[4] = {};
  float mrun = -1e30f, lrun = 0.f;      // per-lane state for q = qgb + col
  unsigned short* pwv = pw[w];

  /* stage tile kv0 into buffer buf: each wave moves 2KB of K + 2KB of V.
     Linear LDS dest; global source pre-swizzled so LDS holds byte^((row&7)<<4). */
#define STAGE(buf, kv0) do {                                                   \
    const size_t kg = kbase + (size_t)(kv0) * D_HEAD;                          \
    _Pragma("unroll")                                                          \
    for (int s_ = 0; s_ < 2; ++s_) {                                           \
      int L_ = w * 2048 + s_ * 1024 + lane * 16;                               \
      int g_ = L_ ^ (((L_ >> 7) & 7) << 4);                                    \
      gload_lds16(Kb + kg + (g_ >> 1), &K_lds[buf][w * 1024 + s_ * 512]);      \
      int row_ = g_ >> 7, cb_ = g_ & 127;                                      \
      gload_lds16(Vt + vbase + (size_t)row_ * SEQ + (kv0) + (cb_ >> 1),        \
                  &V_lds[buf][w * 1024 + s_ * 512]);                           \
    }                                                                          \
  } while (0)

  STAGE(0, 0);
  __syncthreads();

  for (int t = 0; t < ntiles; ++t) {
    const int cur = t & 1;
    const int kv0 = t * 64;
    if (t + 1 < ntiles) STAGE(cur ^ 1, (t + 1) * 64);

    /* S^T = K Q^T : lane holds S[kv = kv0+16nt+4grp+r][q = qgb+col] */
    floatx4 st[4];
    #pragma unroll
    for (int nt = 0; nt < 4; ++nt) {
      int r0 = (nt * 16 + col) * 64;
      int sw = (col & 7) << 3;
      shortx8 kf0 = *(const shortx8*)&K_lds[cur][(r0 + grp * 8) ^ sw];
      shortx8 kf1 = *(const shortx8*)&K_lds[cur][(r0 + 32 + grp * 8) ^ sw];
      floatx4 s = {};
      s = __builtin_amdgcn_mfma_f32_16x16x32_bf16(kf0, qf0, s, 0, 0, 0);
      s = __builtin_amdgcn_mfma_f32_16x16x32_bf16(kf1, qf1, s, 0, 0, 0);
      st[nt] = s;
    }
    /* causal mask: only the last tile (kv0 == q0) can clip this wave's rows */
    float tmax = -1e30f;
    if (t == ntiles - 1) {
      const int q = qgb + col;
      #pragma unroll
      for (int nt = 0; nt < 4; ++nt)
        #pragma unroll
        for (int r = 0; r < 4; ++r) {
          int kv = kv0 + nt * 16 + grp * 4 + r;
          float sv = (kv <= q) ? st[nt][r] : -1e30f;
          st[nt][r] = sv;
          tmax = fmaxf(tmax, sv);
        }
    } else {
      #pragma unroll
      for (int nt = 0; nt < 4; ++nt)
        #pragma unroll
        for (int r = 0; r < 4; ++r) tmax = fmaxf(tmax, st[nt][r]);
    }
    tmax = fmaxf(tmax, __shfl_xor(tmax, 16));
    tmax = fmaxf(tmax, __shfl_xor(tmax, 32));
    const float mnew  = fmaxf(mrun, tmax);
    const float alpha = EXP2(mrun - mnew);
    mrun = mnew;
    float rs = 0.f;
    #pragma unroll
    for (int nt = 0; nt < 4; ++nt)
      #pragma unroll
      for (int r = 0; r < 4; ++r) {
        float pv = EXP2(st[nt][r] - mnew);
        st[nt][r] = pv;
        rs += pv;
      }
    rs += __shfl_xor(rs, 16);
    rs += __shfl_xor(rs, 32);
    lrun = lrun * alpha + rs;
    /* rescale accumulator: alpha lives in col-space, acc rows are grp*4+r */
    #pragma unroll
    for (int r = 0; r < 4; ++r) {
      float ar = __shfl(alpha, grp * 4 + r);
      #pragma unroll
      for (int dn = 0; dn < 4; ++dn) acc[dn][r] *= ar;
    }
    /* P -> per-wave LDS (transpose): lane's 4 r-values are consecutive kv */
    #pragma unroll
    for (int nt = 0; nt < 4; ++nt) {
      ushort4 po;
      po.x = f2bf(st[nt][0]); po.y = f2bf(st[nt][1]);
      po.z = f2bf(st[nt][2]); po.w = f2bf(st[nt][3]);
      *(ushort4*)&pwv[col * 136 + nt * 16 + grp * 4] = po;
    }
    /* Z += P V from LDS: A = P[q=col][kv=32m+8grp..], B = V[d=16dn+col][kv] */
    #pragma unroll
    for (int m = 0; m < 2; ++m) {
      shortx8 pf = *(const shortx8*)&pwv[col * 136 + m * 32 + grp * 8];
      #pragma unroll
      for (int dn = 0; dn < 4; ++dn) {
        int vr = (dn * 16 + col) * 64;
        shortx8 vf = *(const shortx8*)&V_lds[cur][(vr + m * 32 + grp * 8) ^ ((col & 7) << 3)];
        acc[dn] = __builtin_amdgcn_mfma_f32_16x16x32_bf16(pf, vf, acc[dn], 0, 0, 0);
      }
    }
    __syncthreads();   /* next tile staged (vmcnt drain) + everyone done with cur */
  }
#undef STAGE

  /* normalize (lrun is col-space; acc rows are grp*4+r) and write Z */
  const int b = bh / N_HEADS, h = bh % N_HEADS;
  #pragma unroll
  for (int r = 0; r < 4; ++r) {
    float lr = __shfl(lrun, grp * 4 + r);
    float li = 1.0f / lr;
    int q = qgb + grp * 4 + r;
    #pragma unroll
    for (int dn = 0; dn < 4; ++dn)
      Zb[((size_t)b * SEQ + q) * D_MODEL + h * 64 + dn * 16 + col] = f2bf(acc[dn][r] * li);
  }
}

/* ---------------- output projection: [4096,768] @ [768,768]^T + b_o -> fp32 ----
   128x64 tile, 4 waves (wave-tile 64x32), 384 blocks = 8 XCD chunks x 48. */
__launch_bounds__(256, 4)
__global__ void out_gemm_kernel(const unsigned short* __restrict__ Zb,
                                const unsigned short* __restrict__ Wob,
                                const float* __restrict__ bo,
                                float* __restrict__ Out) {
  __shared__ unsigned short Asub[128 * 32];
  __shared__ unsigned short Bsub[64 * 32];
  const int tid  = threadIdx.x;
  const int wave = tid >> 6;
  const int lane = tid & 63;
  /* 384 blocks = 8 XCD chunks x 48 */
  const int flat = blockIdx.x;
  const int swz  = (flat & 7) * 48 + (flat >> 3);
  const int m0 = (swz / 12) * 128;
  const int n0 = (swz % 12) * 64;
  const int wm = (wave >> 1) * 64;
  const int wn = (wave & 1) * 32;
  const int srow = lane >> 2;
  const int scol = (lane & 3) * 8;
  const int col  = lane & 15;
  const int grp  = lane >> 4;
  floatx4 acc[4][2] = {};
  for (int kt = 0; kt < D_MODEL; kt += 32) {
    #pragma unroll
    for (int i = 0; i < 2; ++i) {
      int g = wave * 2 + i;
      gload_lds16(Zb + (size_t)(m0 + g * 16 + srow) * D_MODEL + kt + scol, &Asub[g * 512]);
    }
    gload_lds16(Wob + (size_t)(n0 + wave * 16 + srow) * D_MODEL + kt + scol, &Bsub[wave * 512]);
    __syncthreads();
    shortx8 af[4], bf[2];
    #pragma unroll
    for (int t = 0; t < 4; ++t)
      af[t] = *(const shortx8*)&Asub[(wm + t * 16 + col) * 32 + grp * 8];
    #pragma unroll
    for (int u = 0; u < 2; ++u)
      bf[u] = *(const shortx8*)&Bsub[(wn + u * 16 + col) * 32 + grp * 8];
    #pragma unroll
    for (int i = 0; i < 4; ++i)
      #pragma unroll
      for (int jj = 0; jj < 2; ++jj)
        acc[i][jj] = __builtin_amdgcn_mfma_f32_16x16x32_bf16(af[i], bf[jj], acc[i][jj], 0, 0, 0);
    __syncthreads();
  }
  #pragma unroll
  for (int i = 0; i < 4; ++i) {
    int mbase = m0 + wm + i * 16 + grp * 4;
    #pragma unroll
    for (int jj = 0; jj < 2; ++jj) {
      int n = n0 + wn + jj * 16 + col;
      float bv = bo[n];
      #pragma unroll
      for (int r = 0; r < 4; ++r)
        Out[(size_t)(mbase + r) * D_MODEL + n] = acc[i][jj][r] + bv;
    }
  }
}

/* ---------------- launcher ---------------- */
extern "C" void kernel_launch(void* const* d_in, const int* in_sizes, int n_in,
                              void* d_out, int out_size, void* d_ws, size_t ws_size,
                              hipStream_t stream) {
  const float* x    = (const float*)d_in[0];
  const float* Wqkv = (const float*)d_in[1];
  const float* bqkv = (const float*)d_in[2];
  const float* Wo   = (const float*)d_in[3];
  const float* bo   = (const float*)d_in[4];
  float* out = (float*)d_out;

  unsigned short* ws = (unsigned short*)d_ws;
  const size_t SZ_X   = (size_t)M_TOTAL * D_MODEL;   // 3,145,728
  const size_t SZ_WQ  = (size_t)N_QKV * D_MODEL;     // 1,769,472
  const size_t SZ_WO  = (size_t)D_MODEL * D_MODEL;   //   589,824
  unsigned short* Xb    = ws;
  unsigned short* Wqkvb = Xb + SZ_X;
  unsigned short* Wob   = Wqkvb + SZ_WQ;
  unsigned short* Qb    = Wob + SZ_WO;
  unsigned short* Kb    = Qb + SZ_X;
  unsigned short* Vt    = Kb + SZ_X;
  unsigned short* Zb    = Vt + SZ_X;

  convert_bf16_kernel<<<dim3(1024), dim3(256), 0, stream>>>(x, Wqkv, Wo, Xb, Wqkvb, Wob);
  qkv_gemm_kernel<<<dim3(8 * 72), dim3(256), 0, stream>>>(
      Xb, Wqkvb, bqkv, Qb, Kb, Vt);
  attn_kernel<<<dim3(8 * 96), dim3(256), 0, stream>>>(Qb, Kb, Vt, Zb);
  out_gemm_kernel<<<dim3(8 * 48), dim3(256), 0, stream>>>(
      Zb, Wob, bo, out);
}

// Round 13
// 153.573 us; speedup vs baseline: 1.5300x; 1.1103x over previous
//
#include <hip/hip_runtime.h>
#include <hip/hip_bf16.h>
#include <stdint.h>

#define D_MODEL 768
#define N_HEADS 12
#define D_HEAD  64
#define BATCH   2
#define SEQ     2048
#define M_TOTAL (BATCH*SEQ)   /* 4096 */
#define N_QKV   (3*D_MODEL)   /* 2304 */

typedef float  floatx4 __attribute__((ext_vector_type(4)));
typedef short  shortx8 __attribute__((ext_vector_type(8)));

#if __has_builtin(__builtin_amdgcn_exp2f)
#define EXP2(x) __builtin_amdgcn_exp2f(x)
#else
#define EXP2(x) exp2f(x)
#endif

/* scale folded into Q: (1/sqrt(64)) * log2(e) so softmax runs in exp2 domain */
#define Q_SCALE 0.18033688011112042f

static __device__ __forceinline__ unsigned short f2bf(float f) {
  __hip_bfloat16 h = __float2bfloat16(f);
  return *reinterpret_cast<unsigned short*>(&h);
}

static __device__ __forceinline__ void gload_lds16(const void* g, void* l) {
  auto gp = reinterpret_cast<const uint32_t __attribute__((address_space(1)))*>(
      reinterpret_cast<uintptr_t>(g));
  auto lp = reinterpret_cast<uint32_t __attribute__((address_space(3)))*>(
      reinterpret_cast<uintptr_t>(l));
  __builtin_amdgcn_global_load_lds(gp, lp, 16, 0, 0);
}

/* ---------------- convert fp32 -> bf16 (x, W_qkv, W_o) ---------------- */
__global__ void convert_bf16_kernel(const float* __restrict__ x,
                                    const float* __restrict__ wqkv,
                                    const float* __restrict__ wo,
                                    unsigned short* __restrict__ xb,
                                    unsigned short* __restrict__ wqkvb,
                                    unsigned short* __restrict__ wob) {
  const int NX = M_TOTAL * D_MODEL / 4;   // 786432
  const int NW = N_QKV * D_MODEL / 4;     // 442368
  const int NO = D_MODEL * D_MODEL / 4;   // 147456
  const int total = NX + NW + NO;
  for (int i = blockIdx.x * blockDim.x + threadIdx.x; i < total;
       i += gridDim.x * blockDim.x) {
    const float4* src; unsigned short* dst; int j;
    if (i < NX)            { src = (const float4*)x;    dst = xb;    j = i; }
    else if (i < NX + NW)  { src = (const float4*)wqkv; dst = wqkvb; j = i - NX; }
    else                   { src = (const float4*)wo;   dst = wob;   j = i - NX - NW; }
    float4 v = src[j];
    ushort4 o;
    o.x = f2bf(v.x); o.y = f2bf(v.y); o.z = f2bf(v.z); o.w = f2bf(v.w);
    *(ushort4*)(dst + (size_t)j * 4) = o;
  }
}

/* ---------------- QKV projection GEMM: [4096,768] @ [2304,768]^T ----------------
   128x128 tile, BK=32, 4 waves (2x2, each 64x64, 4x4 acc), DOUBLE-BUFFERED
   staging (stage-next || compute-cur, 1 barrier/K-step). 576 blocks = 8 XCD x 72. */
__launch_bounds__(256, 3)
__global__ void qkv_gemm_kernel(const unsigned short* __restrict__ Xb,
                                const unsigned short* __restrict__ Wb,
                                const float* __restrict__ bias,
                                unsigned short* __restrict__ Qb,
                                unsigned short* __restrict__ Kb,
                                unsigned short* __restrict__ Vt) {
  __shared__ unsigned short Asub[2][128 * 32];
  __shared__ unsigned short Bsub[2][128 * 32];
  const int tid  = threadIdx.x;
  const int wave = tid >> 6;
  const int lane = tid & 63;
  /* 576 blocks = 8 XCD chunks x 72 */
  const int flat = blockIdx.x;
  const int swz  = (flat & 7) * 72 + (flat >> 3);
  const int m0 = (swz / 18) * 128;
  const int n0 = (swz % 18) * 128;
  const int wm = (wave >> 1) * 64;
  const int wn = (wave & 1) * 64;
  const int srow = lane >> 2;          // 0..15
  const int scol = (lane & 3) * 8;     // k element offset
  const int col  = lane & 15;
  const int grp  = lane >> 4;
  floatx4 acc[4][4] = {};

#define QSTAGE(buf, kt) do {                                                     \
    _Pragma("unroll")                                                            \
    for (int i_ = 0; i_ < 2; ++i_) {                                             \
      int c_ = wave * 2 + i_;                                                    \
      int row_ = c_ * 16 + srow;                                                 \
      gload_lds16(Xb + (size_t)(m0 + row_) * D_MODEL + (kt) + scol,              \
                  &Asub[buf][c_ * 512]);                                         \
      gload_lds16(Wb + (size_t)(n0 + row_) * D_MODEL + (kt) + scol,              \
                  &Bsub[buf][c_ * 512]);                                         \
    }                                                                            \
  } while (0)

  QSTAGE(0, 0);
  __syncthreads();
  for (int kt = 0; kt < D_MODEL; kt += 32) {
    const int cur = (kt >> 5) & 1;
    if (kt + 32 < D_MODEL) QSTAGE(cur ^ 1, kt + 32);
    shortx8 af[4], bf[4];
    #pragma unroll
    for (int t = 0; t < 4; ++t) {
      af[t] = *(const shortx8*)&Asub[cur][(wm + t * 16 + col) * 32 + grp * 8];
      bf[t] = *(const shortx8*)&Bsub[cur][(wn + t * 16 + col) * 32 + grp * 8];
    }
    #pragma unroll
    for (int i = 0; i < 4; ++i)
      #pragma unroll
      for (int j = 0; j < 4; ++j)
        acc[i][j] = __builtin_amdgcn_mfma_f32_16x16x32_bf16(af[i], bf[j], acc[i][j], 0, 0, 0);
    __syncthreads();   /* next-tile staging landed + all reads of cur done */
  }
#undef QSTAGE

  /* epilogue: route to Q / K / Vt */
  #pragma unroll
  for (int i = 0; i < 4; ++i) {
    int mbase = m0 + wm + i * 16 + grp * 4;
    int b = mbase >> 11;
    int s = mbase & 2047;
    #pragma unroll
    for (int j = 0; j < 4; ++j) {
      int n   = n0 + wn + j * 16 + col;
      int sel = n / D_MODEL;
      int c   = n % D_MODEL;
      int h   = c >> 6, d = c & 63;
      int bh  = b * N_HEADS + h;
      float bv = bias[n];
      if (sel == 0) {
        #pragma unroll
        for (int r = 0; r < 4; ++r)
          Qb[((size_t)bh * SEQ + s + r) * D_HEAD + d] = f2bf((acc[i][j][r] + bv) * Q_SCALE);
      } else if (sel == 1) {
        #pragma unroll
        for (int r = 0; r < 4; ++r)
          Kb[((size_t)bh * SEQ + s + r) * D_HEAD + d] = f2bf(acc[i][j][r] + bv);
      } else {
        ushort4 o;
        o.x = f2bf(acc[i][j][0] + bv);
        o.y = f2bf(acc[i][j][1] + bv);
        o.z = f2bf(acc[i][j][2] + bv);
        o.w = f2bf(acc[i][j][3] + bv);
        *(ushort4*)&Vt[((size_t)bh * D_HEAD + d) * SEQ + s] = o;
      }
    }
  }
}

/* ---------------- causal flash attention ----------------
   4 waves/block, QBLK=64, KVBLK=64 staged in LDS (double-buffered, XOR-swizzle
   involution), swapped QK^T, exp2 domain — structure as R11 (verified).
   BALANCED grid: 384 blocks = 8 XCD x 48; block handles the q-tile PAIR
   (p, 31-p) -> exactly 33 tile-units of work per block (kills the per-CU
   same-size clustering that capped R12 at Occupancy 14.8%). */
__launch_bounds__(256, 3)
__global__ void attn_kernel(const unsigned short* __restrict__ Qb,
                            const unsigned short* __restrict__ Kb,
                            const unsigned short* __restrict__ Vt,
                            unsigned short* __restrict__ Zb) {
  __shared__ unsigned short K_lds[2][64 * 64];
  __shared__ unsigned short V_lds[2][64 * 64];
  __shared__ unsigned short pw[4][16 * 136];
  const int tid  = threadIdx.x;
  const int w    = tid >> 6;
  const int lane = tid & 63;
  const int col  = lane & 15;
  const int grp  = lane >> 4;

  /* block map: 384 = 8 XCD chunks x 48 (3 heads each, 16 pair-blocks/head) */
  const int i  = blockIdx.x;
  const int u  = (i & 7) * 48 + (i >> 3);
  const int bh = u >> 4;
  const int p  = u & 15;

  const size_t kbase = (size_t)bh * SEQ * D_HEAD;      // K element base for head
  const size_t vbase = (size_t)bh * D_HEAD * SEQ;      // Vt element base for head
  const int b = bh / N_HEADS, h = bh % N_HEADS;
  unsigned short* pwv = pw[w];

#define STAGE(buf, kv0) do {                                                   \
    const size_t kg = kbase + (size_t)(kv0) * D_HEAD;                          \
    _Pragma("unroll")                                                          \
    for (int s_ = 0; s_ < 2; ++s_) {                                           \
      int L_ = w * 2048 + s_ * 1024 + lane * 16;                               \
      int g_ = L_ ^ (((L_ >> 7) & 7) << 4);                                    \
      gload_lds16(Kb + kg + (g_ >> 1), &K_lds[buf][w * 1024 + s_ * 512]);      \
      int row_ = g_ >> 7, cb_ = g_ & 127;                                      \
      gload_lds16(Vt + vbase + (size_t)row_ * SEQ + (kv0) + (cb_ >> 1),        \
                  &V_lds[buf][w * 1024 + s_ * 512]);                           \
    }                                                                          \
  } while (0)

  for (int pass = 0; pass < 2; ++pass) {
    const int qb = pass ? (31 - p) : p;
    const int q0 = qb * 64;
    const int qgb = q0 + w * 16;
    const int ntiles = qb + 1;

    const unsigned short* Qrow = Qb + ((size_t)bh * SEQ + qgb + col) * D_HEAD;
    const shortx8 qf0 = *(const shortx8*)(Qrow + grp * 8);
    const shortx8 qf1 = *(const shortx8*)(Qrow + 32 + grp * 8);

    floatx4 acc[4] = {};
    float mrun = -1e30f, lrun = 0.f;   // per-lane state for q = qgb + col

    STAGE(0, 0);
    __syncthreads();

    for (int t = 0; t < ntiles; ++t) {
      const int cur = t & 1;
      const int kv0 = t * 64;
      if (t + 1 < ntiles) STAGE(cur ^ 1, (t + 1) * 64);

      /* S^T = K Q^T : lane holds S[kv = kv0+16nt+4grp+r][q = qgb+col] */
      floatx4 st[4];
      #pragma unroll
      for (int nt = 0; nt < 4; ++nt) {
        int r0 = (nt * 16 + col) * 64;
        int sw = (col & 7) << 3;
        shortx8 kf0 = *(const shortx8*)&K_lds[cur][(r0 + grp * 8) ^ sw];
        shortx8 kf1 = *(const shortx8*)&K_lds[cur][(r0 + 32 + grp * 8) ^ sw];
        floatx4 s = {};
        s = __builtin_amdgcn_mfma_f32_16x16x32_bf16(kf0, qf0, s, 0, 0, 0);
        s = __builtin_amdgcn_mfma_f32_16x16x32_bf16(kf1, qf1, s, 0, 0, 0);
        st[nt] = s;
      }
      /* causal mask: only the last tile can clip this wave's rows */
      float tmax = -1e30f;
      if (t == ntiles - 1) {
        const int q = qgb + col;
        #pragma unroll
        for (int nt = 0; nt < 4; ++nt)
          #pragma unroll
          for (int r = 0; r < 4; ++r) {
            int kv = kv0 + nt * 16 + grp * 4 + r;
            float sv = (kv <= q) ? st[nt][r] : -1e30f;
            st[nt][r] = sv;
            tmax = fmaxf(tmax, sv);
          }
      } else {
        #pragma unroll
        for (int nt = 0; nt < 4; ++nt)
          #pragma unroll
          for (int r = 0; r < 4; ++r) tmax = fmaxf(tmax, st[nt][r]);
      }
      tmax = fmaxf(tmax, __shfl_xor(tmax, 16));
      tmax = fmaxf(tmax, __shfl_xor(tmax, 32));
      const float mnew  = fmaxf(mrun, tmax);
      const float alpha = EXP2(mrun - mnew);
      mrun = mnew;
      float rs = 0.f;
      #pragma unroll
      for (int nt = 0; nt < 4; ++nt)
        #pragma unroll
        for (int r = 0; r < 4; ++r) {
          float pv = EXP2(st[nt][r] - mnew);
          st[nt][r] = pv;
          rs += pv;
        }
      rs += __shfl_xor(rs, 16);
      rs += __shfl_xor(rs, 32);
      lrun = lrun * alpha + rs;
      /* rescale accumulator: alpha lives in col-space, acc rows are grp*4+r */
      #pragma unroll
      for (int r = 0; r < 4; ++r) {
        float ar = __shfl(alpha, grp * 4 + r);
        #pragma unroll
        for (int dn = 0; dn < 4; ++dn) acc[dn][r] *= ar;
      }
      /* P -> per-wave LDS (transpose): lane's 4 r-values are consecutive kv */
      #pragma unroll
      for (int nt = 0; nt < 4; ++nt) {
        ushort4 po;
        po.x = f2bf(st[nt][0]); po.y = f2bf(st[nt][1]);
        po.z = f2bf(st[nt][2]); po.w = f2bf(st[nt][3]);
        *(ushort4*)&pwv[col * 136 + nt * 16 + grp * 4] = po;
      }
      /* Z += P V from LDS */
      #pragma unroll
      for (int m = 0; m < 2; ++m) {
        shortx8 pf = *(const shortx8*)&pwv[col * 136 + m * 32 + grp * 8];
        #pragma unroll
        for (int dn = 0; dn < 4; ++dn) {
          int vr = (dn * 16 + col) * 64;
          shortx8 vf = *(const shortx8*)&V_lds[cur][(vr + m * 32 + grp * 8) ^ ((col & 7) << 3)];
          acc[dn] = __builtin_amdgcn_mfma_f32_16x16x32_bf16(pf, vf, acc[dn], 0, 0, 0);
        }
      }
      __syncthreads();   /* next tile staged + everyone done with cur */
    }

    /* normalize and write Z */
    #pragma unroll
    for (int r = 0; r < 4; ++r) {
      float lr = __shfl(lrun, grp * 4 + r);
      float li = 1.0f / lr;
      int q = qgb + grp * 4 + r;
      #pragma unroll
      for (int dn = 0; dn < 4; ++dn)
        Zb[((size_t)b * SEQ + q) * D_MODEL + h * 64 + dn * 16 + col] = f2bf(acc[dn][r] * li);
    }
  }
#undef STAGE
}

/* ---------------- output projection: [4096,768] @ [768,768]^T + b_o -> fp32 ----
   128x64 tile, 4 waves (wave-tile 64x32), DOUBLE-BUFFERED staging.
   384 blocks = 8 XCD chunks x 48. */
__launch_bounds__(256, 4)
__global__ void out_gemm_kernel(const unsigned short* __restrict__ Zb,
                                const unsigned short* __restrict__ Wob,
                                const float* __restrict__ bo,
                                float* __restrict__ Out) {
  __shared__ unsigned short Asub[2][128 * 32];
  __shared__ unsigned short Bsub[2][64 * 32];
  const int tid  = threadIdx.x;
  const int wave = tid >> 6;
  const int lane = tid & 63;
  /* 384 blocks = 8 XCD chunks x 48 */
  const int flat = blockIdx.x;
  const int swz  = (flat & 7) * 48 + (flat >> 3);
  const int m0 = (swz / 12) * 128;
  const int n0 = (swz % 12) * 64;
  const int wm = (wave >> 1) * 64;
  const int wn = (wave & 1) * 32;
  const int srow = lane >> 2;
  const int scol = (lane & 3) * 8;
  const int col  = lane & 15;
  const int grp  = lane >> 4;
  floatx4 acc[4][2] = {};

#define OSTAGE(buf, kt) do {                                                     \
    _Pragma("unroll")                                                            \
    for (int i_ = 0; i_ < 2; ++i_) {                                             \
      int g_ = wave * 2 + i_;                                                    \
      gload_lds16(Zb + (size_t)(m0 + g_ * 16 + srow) * D_MODEL + (kt) + scol,    \
                  &Asub[buf][g_ * 512]);                                         \
    }                                                                            \
    gload_lds16(Wob + (size_t)(n0 + wave * 16 + srow) * D_MODEL + (kt) + scol,   \
                &Bsub[buf][wave * 512]);                                         \
  } while (0)

  OSTAGE(0, 0);
  __syncthreads();
  for (int kt = 0; kt < D_MODEL; kt += 32) {
    const int cur = (kt >> 5) & 1;
    if (kt + 32 < D_MODEL) OSTAGE(cur ^ 1, kt + 32);
    shortx8 af[4], bf[2];
    #pragma unroll
    for (int t = 0; t < 4; ++t)
      af[t] = *(const shortx8*)&Asub[cur][(wm + t * 16 + col) * 32 + grp * 8];
    #pragma unroll
    for (int u = 0; u < 2; ++u)
      bf[u] = *(const shortx8*)&Bsub[cur][(wn + u * 16 + col) * 32 + grp * 8];
    #pragma unroll
    for (int i = 0; i < 4; ++i)
      #pragma unroll
      for (int jj = 0; jj < 2; ++jj)
        acc[i][jj] = __builtin_amdgcn_mfma_f32_16x16x32_bf16(af[i], bf[jj], acc[i][jj], 0, 0, 0);
    __syncthreads();
  }
#undef OSTAGE

  #pragma unroll
  for (int i = 0; i < 4; ++i) {
    int mbase = m0 + wm + i * 16 + grp * 4;
    #pragma unroll
    for (int jj = 0; jj < 2; ++jj) {
      int n = n0 + wn + jj * 16 + col;
      float bv = bo[n];
      #pragma unroll
      for (int r = 0; r < 4; ++r)
        Out[(size_t)(mbase + r) * D_MODEL + n] = acc[i][jj][r] + bv;
    }
  }
}

/* ---------------- launcher ---------------- */
extern "C" void kernel_launch(void* const* d_in, const int* in_sizes, int n_in,
                              void* d_out, int out_size, void* d_ws, size_t ws_size,
                              hipStream_t stream) {
  const float* x    = (const float*)d_in[0];
  const float* Wqkv = (const float*)d_in[1];
  const float* bqkv = (const float*)d_in[2];
  const float* Wo   = (const float*)d_in[3];
  const float* bo   = (const float*)d_in[4];
  float* out = (float*)d_out;

  unsigned short* ws = (unsigned short*)d_ws;
  const size_t SZ_X   = (size_t)M_TOTAL * D_MODEL;   // 3,145,728
  const size_t SZ_WQ  = (size_t)N_QKV * D_MODEL;     // 1,769,472
  const size_t SZ_WO  = (size_t)D_MODEL * D_MODEL;   //   589,824
  unsigned short* Xb    = ws;
  unsigned short* Wqkvb = Xb + SZ_X;
  unsigned short* Wob   = Wqkvb + SZ_WQ;
  unsigned short* Qb    = Wob + SZ_WO;
  unsigned short* Kb    = Qb + SZ_X;
  unsigned short* Vt    = Kb + SZ_X;
  unsigned short* Zb    = Vt + SZ_X;

  convert_bf16_kernel<<<dim3(1024), dim3(256), 0, stream>>>(x, Wqkv, Wo, Xb, Wqkvb, Wob);
  qkv_gemm_kernel<<<dim3(8 * 72), dim3(256), 0, stream>>>(
      Xb, Wqkvb, bqkv, Qb, Kb, Vt);
  attn_kernel<<<dim3(8 * 48), dim3(256), 0, stream>>>(Qb, Kb, Vt, Zb);
  out_gemm_kernel<<<dim3(8 * 48), dim3(256), 0, stream>>>(
      Zb, Wob, bo, out);
}